// Round 2
// baseline (329.318 us; speedup 1.0000x reference)
//
#include <hip/hip_runtime.h>
#include <math.h>

// SoftKConv: h = feat@W (+ bf16 hi/lo split precomputed in the GEMM epilogue);
// per node: gather k=32 neighbor fragment rows straight from global (h_hi/h_lo),
// pairwise distances via MFMA bf16x3 fp32-emulation, weighted medoid cost,
// softmax -> weighted combination of neighbor embeddings (fp32 h re-read).
//
// softk: 2 nodes per 128-thread block (1 wave per node). LDS = dist+sq only
// (8.7 KB/block) -> occupancy jumps from 19% (22KB blocks) to ~50%.

typedef __attribute__((ext_vector_type(8)))  short  short8;   // 8 bf16 in 4 VGPRs
typedef __attribute__((ext_vector_type(16))) float  f32x16;   // MFMA 32x32 accumulator

#define NK   32
#define DIM  128

static __device__ __forceinline__ short f2bf_rne(float x) {
    union { float f; unsigned u; } v; v.f = x;
    unsigned r = v.u + 0x7FFFu + ((v.u >> 16) & 1u);
    return (short)(r >> 16);
}
static __device__ __forceinline__ float bf2f(short b) {
    union { float f; unsigned u; } v; v.u = ((unsigned)(unsigned short)b) << 16;
    return v.f;
}

// ---------------- Kernel 1: h = feat @ W  (N x 128) @ (128 x 128) ----------
// Also emits h_hi / h_lo bf16 split (converted ONCE per row here, instead of
// ~32x per row inside softk).
__global__ __launch_bounds__(256) void gemm128(
    const float* __restrict__ A, const float* __restrict__ W,
    float* __restrict__ H, short* __restrict__ Hhi, short* __restrict__ Hlo,
    int n)
{
    __shared__ __align__(16) float sW[32][132];  // K-chunk of W, row-major
    __shared__ __align__(16) float sF[64][36];   // 64 rows x 32 K-chunk of feat

    const int t  = threadIdx.x;
    const int r0 = blockIdx.x * 64;
    const int tc = t & 15;    // col group: 8 cols
    const int tr = t >> 4;    // row group: 4 rows

    float acc[4][8];
#pragma unroll
    for (int i = 0; i < 4; ++i)
#pragma unroll
        for (int j = 0; j < 8; ++j) acc[i][j] = 0.0f;

    for (int ck = 0; ck < 4; ++ck) {
#pragma unroll
        for (int i = 0; i < 4; ++i) {
            int e  = t + i * 256;
            int wr = e >> 5, wc = (e & 31) << 2;
            *reinterpret_cast<float4*>(&sW[wr][wc]) =
                *reinterpret_cast<const float4*>(W + (ck * 32 + wr) * 128 + wc);
        }
#pragma unroll
        for (int i = 0; i < 2; ++i) {
            int e  = t + i * 256;
            int fr = e >> 3, fc = (e & 7) << 2;
            int gr = r0 + fr;
            float4 v = make_float4(0.f, 0.f, 0.f, 0.f);
            if (gr < n)
                v = *reinterpret_cast<const float4*>(A + (size_t)gr * 128 + ck * 32 + fc);
            *reinterpret_cast<float4*>(&sF[fr][fc]) = v;
        }
        __syncthreads();

#pragma unroll
        for (int c = 0; c < 32; ++c) {
            float b[8];
            *reinterpret_cast<float4*>(&b[0]) = *reinterpret_cast<const float4*>(&sW[c][tc * 8]);
            *reinterpret_cast<float4*>(&b[4]) = *reinterpret_cast<const float4*>(&sW[c][tc * 8 + 4]);
#pragma unroll
            for (int i = 0; i < 4; ++i) {
                float a = sF[tr * 4 + i][c];
#pragma unroll
                for (int j = 0; j < 8; ++j) acc[i][j] = fmaf(a, b[j], acc[i][j]);
            }
        }
        __syncthreads();
    }

#pragma unroll
    for (int i = 0; i < 4; ++i) {
        int gr = r0 + tr * 4 + i;
        if (gr < n) {
            float4 v0 = {acc[i][0], acc[i][1], acc[i][2], acc[i][3]};
            float4 v1 = {acc[i][4], acc[i][5], acc[i][6], acc[i][7]};
            *reinterpret_cast<float4*>(H + (size_t)gr * 128 + tc * 8)     = v0;
            *reinterpret_cast<float4*>(H + (size_t)gr * 128 + tc * 8 + 4) = v1;
            short8 hi8, lo8;
#pragma unroll
            for (int j = 0; j < 8; ++j) {
                short hb = f2bf_rne(acc[i][j]);
                hi8[j] = hb;
                lo8[j] = f2bf_rne(acc[i][j] - bf2f(hb));
            }
            *reinterpret_cast<short8*>(Hhi + (size_t)gr * 128 + tc * 8) = hi8;
            *reinterpret_cast<short8*>(Hlo + (size_t)gr * 128 + tc * 8) = lo8;
        }
    }
}

// ---------------- Kernel 2: per-node soft medoid ---------------------------
// 128 threads = 2 waves = 2 independent nodes. Cross-lane state via shuffles.
__global__ __launch_bounds__(128, 4) void softk(
    const float* __restrict__ h, const short* __restrict__ hhi,
    const short* __restrict__ hlo, const float* __restrict__ bias,
    const float* __restrict__ tkw, const int* __restrict__ idx,
    float* __restrict__ out, int n)
{
    __shared__ float dist[2][NK][NK + 1];
    __shared__ float sq[2][NK];

    const int wave = threadIdx.x >> 6;
    const int lane = threadIdx.x & 63;
    int node = blockIdx.x * 2 + wave;
    if (node >= n) node = n - 1;            // duplicate compute; benign

    const int row   = lane & 31;
    const int hf    = lane >> 5;
    const int khalf = hf * 8;               // A/B-fragment k-offset

    // lanes 0..31 own neighbor k=lane
    int id_l = 0, mk_l = 0; float w_l = 0.0f;
    if (lane < NK) {
        int id = idx[(size_t)node * NK + lane];
        mk_l = (id < 0) ? 1 : 0;
        id_l = mk_l ? 0 : id;
        w_l  = mk_l ? 0.0f : tkw[(size_t)node * NK + lane];
    }
    const int idr = __shfl(id_l, row, 64);  // this lane's fragment row id

    // ---- fragment loads straight from global (no LDS, no conversion) ----
    const short* ph = hhi + (size_t)idr * DIM + khalf;
    const short* pl = hlo + (size_t)idr * DIM + khalf;
    short8 fh[8], fl[8];
#pragma unroll
    for (int s = 0; s < 8; ++s) {
        fh[s] = *reinterpret_cast<const short8*>(ph + s * 16);
        fl[s] = *reinterpret_cast<const short8*>(pl + s * 16);
    }

    // gram = FK @ FK^T, bf16x3 (drop lo*lo)
    f32x16 acc = {0.f,0.f,0.f,0.f,0.f,0.f,0.f,0.f,0.f,0.f,0.f,0.f,0.f,0.f,0.f,0.f};
#pragma unroll
    for (int s = 0; s < 8; ++s) {
        acc = __builtin_amdgcn_mfma_f32_32x32x16_bf16(fh[s], fh[s], acc, 0, 0, 0);
        acc = __builtin_amdgcn_mfma_f32_32x32x16_bf16(fh[s], fl[s], acc, 0, 0, 0);
        acc = __builtin_amdgcn_mfma_f32_32x32x16_bf16(fl[s], fh[s], acc, 0, 0, 0);
    }

    // C/D layout: col = lane&31, rowD = (reg&3) + 8*(reg>>2) + 4*hf
#pragma unroll
    for (int reg = 0; reg < 16; ++reg) {
        int rD = (reg & 3) + 8 * (reg >> 2) + 4 * hf;
        if (rD == row) sq[wave][row] = acc[reg];   // diagonal = |fk_row|^2
    }
    __syncthreads();

#pragma unroll
    for (int reg = 0; reg < 16; ++reg) {
        int rD = (reg & 3) + 8 * (reg >> 2) + 4 * hf;
        float d2 = fmaf(-2.0f, acc[reg], sq[wave][rD] + sq[wave][row]);
        dist[wave][rD][row] = __builtin_amdgcn_sqrtf(fmaxf(d2, 0.0f));
    }
    __syncthreads();

    // dagg[k=row] = sum_m w[m] * dist[row][m]; halves split m, combine.
    const int m0 = hf * 16;
    float part = 0.0f;
#pragma unroll
    for (int j = 0; j < 16; ++j) {
        int m = m0 + j;
        float wm = __shfl(w_l, m, 64);
        part = fmaf(wm, dist[wave][row][m], part);
    }
    float s = part + __shfl_xor(part, 32, 64);

    const int mkk = __shfl(mk_l, row, 64);
    if (mkk || !(s < 3.4028235e38f)) s = 3.4028235e38f;

    // softmax over the 32 k-values (duplicated across halves)
    float x  = -s;
    float mx = x;
#pragma unroll
    for (int o = 16; o > 0; o >>= 1) mx = fmaxf(mx, __shfl_xor(mx, o, 32));
    float e  = __expf(x - mx);
    float se = e;
#pragma unroll
    for (int o = 16; o > 0; o >>= 1) se += __shfl_xor(se, o, 32);
    float r = e * __builtin_amdgcn_rcpf(se);
    r *= __shfl(w_l, row, 64);
    float sr = r;
#pragma unroll
    for (int o = 16; o > 0; o >>= 1) sr += __shfl_xor(sr, o, 32);
    r = r * __builtin_amdgcn_rcpf(sr);
    if (mkk) r = 0.0f;

    // epilogue: out[d] = sum_k r_k * h[idx_k][d] + bias[d]; 2 cols/lane
    float o0 = 0.0f, o1 = 0.0f;
#pragma unroll
    for (int k = 0; k < NK; ++k) {
        int   idk = __shfl(id_l, k, 64);
        float rk  = __shfl(r, k, 64);
        const float* pr = h + (size_t)idk * DIM;
        o0 = fmaf(rk, pr[lane], o0);
        o1 = fmaf(rk, pr[lane + 64], o1);
    }
    size_t base = (size_t)node * DIM;
    out[base + lane]      = o0 + bias[lane];
    out[base + lane + 64] = o1 + bias[lane + 64];
}

extern "C" void kernel_launch(void* const* d_in, const int* in_sizes, int n_in,
                              void* d_out, int out_size, void* d_ws, size_t ws_size,
                              hipStream_t stream) {
    const float* feat = (const float*)d_in[0];
    const float* W    = (const float*)d_in[1];
    const float* bias = (const float*)d_in[2];
    const float* tkw  = (const float*)d_in[3];
    const int*   idx  = (const int*)d_in[4];
    float* out = (float*)d_out;

    const int n = in_sizes[0] / DIM;        // 50000
    float* h   = (float*)d_ws;                              // n*128*4  = 25.6 MB
    short* hhi = (short*)((char*)d_ws + (size_t)n * DIM * 4);     // 12.8 MB
    short* hlo = hhi + (size_t)n * DIM;                           // 12.8 MB

    const int gblocks = (n + 63) / 64;
    gemm128<<<gblocks, 256, 0, stream>>>(feat, W, h, hhi, hlo, n);
    softk<<<(n + 1) / 2, 128, 0, stream>>>(h, hhi, hlo, bias, tkw, idx, out, n);
}

// Round 3
// 181.218 us; speedup vs baseline: 1.8173x; 1.8173x over previous
//
#include <hip/hip_runtime.h>
#include <math.h>

// SoftKConv, round 3.
// Binding constraint (round-2 rocprof): gather bytes/node. Fix: store h in
// f16 only (consistent rounding => exact algorithm on perturbed embeddings,
// rel 2^-11; propagated out-err ~5e-3 << 7.7e-2 threshold). softk gathers
// 8 KB/node once; gram via f16 MFMA; epilogue reconstructs the weighted sum
// from the SAME register fragments via a 5-stage recursive-halving
// reduce-scatter across the 32 lanes (no second gather, no fk LDS).

typedef __attribute__((ext_vector_type(8)))  _Float16 half8;   // 8 f16 = 4 VGPRs
typedef __attribute__((ext_vector_type(16))) float    f32x16;  // MFMA 32x32 acc

#define NK   32
#define DIM  128

// ---------------- Kernel 1: h = feat @ W -> f16  ---------------------------
__global__ __launch_bounds__(256) void gemm128(
    const float* __restrict__ A, const float* __restrict__ W,
    _Float16* __restrict__ Hq, int n)
{
    __shared__ __align__(16) float sW[32][132];
    __shared__ __align__(16) float sF[64][36];

    const int t  = threadIdx.x;
    const int r0 = blockIdx.x * 64;
    const int tc = t & 15;    // col group: 8 cols
    const int tr = t >> 4;    // row group: 4 rows

    float acc[4][8];
#pragma unroll
    for (int i = 0; i < 4; ++i)
#pragma unroll
        for (int j = 0; j < 8; ++j) acc[i][j] = 0.0f;

    for (int ck = 0; ck < 4; ++ck) {
#pragma unroll
        for (int i = 0; i < 4; ++i) {
            int e  = t + i * 256;
            int wr = e >> 5, wc = (e & 31) << 2;
            *reinterpret_cast<float4*>(&sW[wr][wc]) =
                *reinterpret_cast<const float4*>(W + (ck * 32 + wr) * 128 + wc);
        }
#pragma unroll
        for (int i = 0; i < 2; ++i) {
            int e  = t + i * 256;
            int fr = e >> 3, fc = (e & 7) << 2;
            int gr = r0 + fr;
            float4 v = make_float4(0.f, 0.f, 0.f, 0.f);
            if (gr < n)
                v = *reinterpret_cast<const float4*>(A + (size_t)gr * 128 + ck * 32 + fc);
            *reinterpret_cast<float4*>(&sF[fr][fc]) = v;
        }
        __syncthreads();

#pragma unroll
        for (int c = 0; c < 32; ++c) {
            float b[8];
            *reinterpret_cast<float4*>(&b[0]) = *reinterpret_cast<const float4*>(&sW[c][tc * 8]);
            *reinterpret_cast<float4*>(&b[4]) = *reinterpret_cast<const float4*>(&sW[c][tc * 8 + 4]);
#pragma unroll
            for (int i = 0; i < 4; ++i) {
                float a = sF[tr * 4 + i][c];
#pragma unroll
                for (int j = 0; j < 8; ++j) acc[i][j] = fmaf(a, b[j], acc[i][j]);
            }
        }
        __syncthreads();
    }

#pragma unroll
    for (int i = 0; i < 4; ++i) {
        int gr = r0 + tr * 4 + i;
        if (gr < n) {
            half8 o;
#pragma unroll
            for (int j = 0; j < 8; ++j) o[j] = (_Float16)acc[i][j];
            *reinterpret_cast<half8*>(Hq + (size_t)gr * 128 + tc * 8) = o;
        }
    }
}

// ---------------- Kernel 2: per-node soft medoid ---------------------------
// 128 threads = 2 waves = 2 independent nodes.
__global__ __launch_bounds__(128, 4) void softk(
    const _Float16* __restrict__ hq, const float* __restrict__ bias,
    const float* __restrict__ tkw, const int* __restrict__ idx,
    float* __restrict__ out, int n)
{
    __shared__ float dist[2][NK][NK + 1];
    __shared__ float sq[2][NK];

    const int wave = threadIdx.x >> 6;
    const int lane = threadIdx.x & 63;
    int node = blockIdx.x * 2 + wave;
    if (node >= n) node = n - 1;            // duplicate compute; benign

    const int row = lane & 31;
    const int hf  = lane >> 5;              // which 8-of-16 k-slice

    // lanes 0..31 own neighbor k=lane
    int id_l = 0, mk_l = 0; float w_l = 0.0f;
    if (lane < NK) {
        int id = idx[(size_t)node * NK + lane];
        mk_l = (id < 0) ? 1 : 0;
        id_l = mk_l ? 0 : id;
        w_l  = mk_l ? 0.0f : tkw[(size_t)node * NK + lane];
    }
    const int idr = __shfl(id_l, row, 64);  // this lane's fragment row id

    // ---- single gather: 8 KB/node, straight into MFMA fragments ----
    const half8* base = reinterpret_cast<const half8*>(hq + (size_t)idr * DIM);
    half8 frag[8];
#pragma unroll
    for (int s = 0; s < 8; ++s) frag[s] = base[2 * s + hf];

    // gram = FK @ FK^T (f16 inputs, fp32 accumulate)
    f32x16 acc = {0.f,0.f,0.f,0.f,0.f,0.f,0.f,0.f,0.f,0.f,0.f,0.f,0.f,0.f,0.f,0.f};
#pragma unroll
    for (int s = 0; s < 8; ++s)
        acc = __builtin_amdgcn_mfma_f32_32x32x16_f16(frag[s], frag[s], acc, 0, 0, 0);

    // C/D layout: col = lane&31, rowD = (reg&3) + 8*(reg>>2) + 4*hf
#pragma unroll
    for (int reg = 0; reg < 16; ++reg) {
        int rD = (reg & 3) + 8 * (reg >> 2) + 4 * hf;
        if (rD == row) sq[wave][row] = acc[reg];   // diagonal = |fk_row|^2
    }
    __syncthreads();

#pragma unroll
    for (int reg = 0; reg < 16; ++reg) {
        int rD = (reg & 3) + 8 * (reg >> 2) + 4 * hf;
        float d2 = fmaf(-2.0f, acc[reg], sq[wave][rD] + sq[wave][row]);
        dist[wave][rD][row] = __builtin_amdgcn_sqrtf(fmaxf(d2, 0.0f));
    }
    __syncthreads();

    // dagg[k=row] = sum_m w[m] * dist[row][m]; halves split m, combine.
    const int m0 = hf * 16;
    float part = 0.0f;
#pragma unroll
    for (int j = 0; j < 16; ++j) {
        int m = m0 + j;
        float wm = __shfl(w_l, m, 64);
        part = fmaf(wm, dist[wave][row][m], part);
    }
    float s = part + __shfl_xor(part, 32, 64);

    const int mkk = __shfl(mk_l, row, 64);
    if (mkk || !(s < 3.4028235e38f)) s = 3.4028235e38f;

    // softmax over the 32 k-values (duplicated across halves)
    float x  = -s;
    float mx = x;
#pragma unroll
    for (int o = 16; o > 0; o >>= 1) mx = fmaxf(mx, __shfl_xor(mx, o, 32));
    float e  = __expf(x - mx);
    float se = e;
#pragma unroll
    for (int o = 16; o > 0; o >>= 1) se += __shfl_xor(se, o, 32);
    float r = e * __builtin_amdgcn_rcpf(se);
    r *= __shfl(w_l, row, 64);
    float sr = r;
#pragma unroll
    for (int o = 16; o > 0; o >>= 1) sr += __shfl_xor(sr, o, 32);
    r = r * __builtin_amdgcn_rcpf(sr);
    if (mkk) r = 0.0f;                      // r == r_{k=row} in every lane

    // ---- epilogue: out[d] = sum_row r_row * fk[row][d], from fragments ----
    // Lane (row,hf) holds fk[row][16s + 8hf + j] in frag[s][j]. Reduce across
    // the 32 rows by recursive halving (reduce-scatter): after 5 stages lane
    // holds full sums for original reg indices {2row, 2row+1}.
    const bool b16 = (row & 16) != 0;
    float red[32];
#pragma unroll
    for (int s = 0; s < 4; ++s) {
#pragma unroll
        for (int j = 0; j < 8; ++j) {
            float vA = (float)frag[s][j]     * r;   // orig reg i = 8s+j
            float vB = (float)frag[s + 4][j] * r;   // orig reg i+32
            float send = b16 ? vA : vB;
            float recv = __shfl_xor(send, 16, 64);
            float keep = b16 ? vB : vA;
            red[8 * s + j] = keep + recv;
        }
    }
    const bool b8 = (row & 8) != 0;
#pragma unroll
    for (int i = 0; i < 16; ++i) {
        float send = b8 ? red[i] : red[i + 16];
        float recv = __shfl_xor(send, 8, 64);
        float keep = b8 ? red[i + 16] : red[i];
        red[i] = keep + recv;
    }
    const bool b4 = (row & 4) != 0;
#pragma unroll
    for (int i = 0; i < 8; ++i) {
        float send = b4 ? red[i] : red[i + 8];
        float recv = __shfl_xor(send, 4, 64);
        float keep = b4 ? red[i + 8] : red[i];
        red[i] = keep + recv;
    }
    const bool b2 = (row & 2) != 0;
#pragma unroll
    for (int i = 0; i < 4; ++i) {
        float send = b2 ? red[i] : red[i + 4];
        float recv = __shfl_xor(send, 2, 64);
        float keep = b2 ? red[i + 4] : red[i];
        red[i] = keep + recv;
    }
    const bool b1 = (row & 1) != 0;
#pragma unroll
    for (int i = 0; i < 2; ++i) {
        float send = b1 ? red[i] : red[i + 2];
        float recv = __shfl_xor(send, 1, 64);
        float keep = b1 ? red[i + 2] : red[i];
        red[i] = keep + recv;
    }
    // lane holds sums for orig regs {2row, 2row+1} ->
    // dim d0 = 16*(row>>2) + 8*hf + 2*(row&3), and d0+1.
    const int d0 = 16 * (row >> 2) + 8 * hf + 2 * (row & 3);
    size_t basep = (size_t)node * DIM + d0;
    float2 ov = { red[0] + bias[d0], red[1] + bias[d0 + 1] };
    *reinterpret_cast<float2*>(out + basep) = ov;
}

extern "C" void kernel_launch(void* const* d_in, const int* in_sizes, int n_in,
                              void* d_out, int out_size, void* d_ws, size_t ws_size,
                              hipStream_t stream) {
    const float* feat = (const float*)d_in[0];
    const float* W    = (const float*)d_in[1];
    const float* bias = (const float*)d_in[2];
    const float* tkw  = (const float*)d_in[3];
    const int*   idx  = (const int*)d_in[4];
    float* out = (float*)d_out;

    const int n = in_sizes[0] / DIM;        // 50000
    _Float16* hq = (_Float16*)d_ws;         // n*128*2 = 12.8 MB of ws

    const int gblocks = (n + 63) / 64;
    gemm128<<<gblocks, 256, 0, stream>>>(feat, W, hq, n);
    softk<<<(n + 1) / 2, 128, 0, stream>>>(hq, bias, tkw, idx, out, n);
}

// Round 4
// 167.016 us; speedup vs baseline: 1.9718x; 1.0850x over previous
//
#include <hip/hip_runtime.h>
#include <math.h>

// SoftKConv, round 4.
// r3 post-mortem: softk VALU-issue-bound (54% busy) — dominant cost was the
// ~400-instr shuffle reduce-scatter epilogue; gemm was fp32-VALU (~30 µs).
// r4: (a) epilogue out = r^T * FK via mfma_32x32x16_f16 (fk staged to LDS
// row-major, B-frags via conflict-free ds_read_u16; all operand layouts
// verified by r1-r3 usage); (b) dagg from registers via bpermuted sq/w —
// no dist LDS, no barriers at all; (c) gemm MFMA-ized (h^T form, A from
// WT-f16, B from feat, no LDS), plus tiny WT prep kernel.

typedef __attribute__((ext_vector_type(4)))  _Float16 half4v;
typedef __attribute__((ext_vector_type(8)))  _Float16 half8;
typedef __attribute__((ext_vector_type(16))) float    f32x16;

#define NK   32
#define DIM  128
#define FKS  136   // LDS row stride in halves: 272 B = 16-B aligned rows;
                   // u16 B-frag reads land on distinct banks (free)

// ---------------- Kernel 0: WT[n][k] = (f16) W[k][n] -----------------------
__global__ __launch_bounds__(256) void prep(const float* __restrict__ W,
                                            _Float16* __restrict__ WT) {
    int t  = blockIdx.x * 256 + threadIdx.x;   // 0..16383
    int nn = t >> 7, k = t & 127;
    WT[t] = (_Float16)W[k * 128 + nn];
}

// ---------------- Kernel 1: h = feat @ W -> f16, MFMA ----------------------
// C[i=hcol][j=hrow]: A[i][k] = WT[i][k], B[k][j] = feat[row j][k].
// Wave w of 4 handles rows r0 = 128*blk + 32w .. +31; lane holds one h-row.
__global__ __launch_bounds__(256) void gemm128(
    const float* __restrict__ A, const _Float16* __restrict__ WT,
    _Float16* __restrict__ Hq, int n)
{
    const int wave = threadIdx.x >> 6;
    const int lane = threadIdx.x & 63;
    const int l31  = lane & 31;
    const int hf   = lane >> 5;

    const int row  = blockIdx.x * 128 + wave * 32 + l31;
    const int rowc = row < n ? row : n - 1;

    f32x16 acc[4];
#pragma unroll
    for (int t = 0; t < 4; ++t)
#pragma unroll
        for (int i = 0; i < 16; ++i) acc[t][i] = 0.0f;

    const float* ap = A + (size_t)rowc * 128 + 8 * hf;
#pragma unroll
    for (int s = 0; s < 8; ++s) {
        // B-frag: feat[row][16s + 8hf + j], j=0..7
        float4 b0 = *reinterpret_cast<const float4*>(ap + 16 * s);
        float4 b1 = *reinterpret_cast<const float4*>(ap + 16 * s + 4);
        half8 bf;
        bf[0] = (_Float16)b0.x; bf[1] = (_Float16)b0.y;
        bf[2] = (_Float16)b0.z; bf[3] = (_Float16)b0.w;
        bf[4] = (_Float16)b1.x; bf[5] = (_Float16)b1.y;
        bf[6] = (_Float16)b1.z; bf[7] = (_Float16)b1.w;
#pragma unroll
        for (int t = 0; t < 4; ++t) {
            half8 af = *reinterpret_cast<const half8*>(
                WT + (size_t)(l31 + 32 * t) * 128 + 16 * s + 8 * hf);
            acc[t] = __builtin_amdgcn_mfma_f32_32x32x16_f16(af, bf, acc[t], 0, 0, 0);
        }
    }

    if (row < n) {
        _Float16* hp = Hq + (size_t)row * 128;
        // reg = 4g+q -> hcol = 32t + 8g + 4hf + q  (4 consecutive cols/run)
#pragma unroll
        for (int t = 0; t < 4; ++t)
#pragma unroll
            for (int g = 0; g < 4; ++g) {
                half4v hv;
#pragma unroll
                for (int q = 0; q < 4; ++q) hv[q] = (_Float16)acc[t][4 * g + q];
                *reinterpret_cast<half4v*>(hp + 32 * t + 8 * g + 4 * hf) = hv;
            }
    }
}

// ---------------- Kernel 2: per-node soft medoid ---------------------------
// 128 threads = 2 waves = 2 independent nodes. No barriers (per-wave LDS
// region; LDS ops are in-order within a wave).
__global__ __launch_bounds__(128, 4) void softk(
    const _Float16* __restrict__ hq, const float* __restrict__ bias,
    const float* __restrict__ tkw, const int* __restrict__ idx,
    float* __restrict__ out, int n)
{
    __shared__ __align__(16) _Float16 fkRM[2][NK][FKS];   // 17408 B

    const int wave = threadIdx.x >> 6;
    const int lane = threadIdx.x & 63;
    int node = blockIdx.x * 2 + wave;
    if (node >= n) node = n - 1;            // duplicate compute; benign

    const int l31 = lane & 31;
    const int hf  = lane >> 5;

    // lanes 0..31 own neighbor k=lane
    int id_l = 0, mk_l = 0; float w_l = 0.0f;
    if (lane < NK) {
        int id = idx[(size_t)node * NK + lane];
        mk_l = (id < 0) ? 1 : 0;
        id_l = mk_l ? 0 : id;
        w_l  = mk_l ? 0.0f : tkw[(size_t)node * NK + lane];
    }
    const int idr = __shfl(id_l, l31, 64);  // this lane's fragment row id

    // single gather: 8 KB/node straight into MFMA A/B fragments
    const half8* bp = reinterpret_cast<const half8*>(hq + (size_t)idr * DIM);
    half8 frag[8];
#pragma unroll
    for (int s = 0; s < 8; ++s) frag[s] = bp[2 * s + hf];

    // gram = FK @ FK^T (f16 in, fp32 acc)
    f32x16 acc;
#pragma unroll
    for (int i = 0; i < 16; ++i) acc[i] = 0.0f;
#pragma unroll
    for (int s = 0; s < 8; ++s)
        acc = __builtin_amdgcn_mfma_f32_32x32x16_f16(frag[s], frag[s], acc, 0, 0, 0);

    // stage fk rows to LDS (row-major) for the epilogue B-frags
#pragma unroll
    for (int s = 0; s < 8; ++s)
        *reinterpret_cast<half8*>(&fkRM[wave][l31][16 * s + 8 * hf]) = frag[s];

    // diagonal: sq[col]; lane (c, bit2(c)) holds it -> exchange across halves
    float dval = acc[0];
#pragma unroll
    for (int reg = 0; reg < 16; ++reg) {
        int rD = (reg & 3) + 8 * (reg >> 2) + 4 * hf;
        if (rD == l31) dval = acc[reg];
    }
    const bool own = (((l31 >> 2) & 1) == hf);
    float oth = __shfl_xor(dval, 32, 64);
    float sqc = own ? dval : oth;           // sq[l31] in every lane

    float wc  = __shfl(w_l,  l31, 64);      // w[l31]
    int   mkc = __shfl(mk_l, l31, 64);

    // dagg[c] = sum_m w_m dist[m][c]  (symmetry: reduce over this lane's regs)
    const int pbase = (lane & 32) + ((lane & 32) >> 3);   // rD source lane base
    float part = 0.0f;
#pragma unroll
    for (int reg = 0; reg < 16; ++reg) {
        const int c = (reg & 3) + 8 * (reg >> 2);
        float sqr = __shfl(sqc, pbase + c, 64);           // sq[rD]
        float wr  = __shfl(wc,  pbase + c, 64);           // w[rD]
        float d2  = fmaf(-2.0f, acc[reg], sqr + sqc);
        part = fmaf(wr, __builtin_amdgcn_sqrtf(fmaxf(d2, 0.0f)), part);
    }
    float sA = part + __shfl_xor(part, 32, 64);
    if (mkc || !(sA < 3.4028235e38f)) sA = 3.4028235e38f;

    // softmax over 32 k (duplicated across halves)
    float x  = -sA;
    float mx = x;
#pragma unroll
    for (int o = 16; o > 0; o >>= 1) mx = fmaxf(mx, __shfl_xor(mx, o, 32));
    float e  = __expf(x - mx);
    float se = e;
#pragma unroll
    for (int o = 16; o > 0; o >>= 1) se += __shfl_xor(se, o, 32);
    float r = e * __builtin_amdgcn_rcpf(se);
    r *= wc;
    float sr = r;
#pragma unroll
    for (int o = 16; o > 0; o >>= 1) sr += __shfl_xor(sr, o, 32);
    r = r * __builtin_amdgcn_rcpf(sr);
    if (mkc) r = 0.0f;                      // r_{k=l31} in every lane

    // ---- epilogue: out = r^T FK via MFMA (A rows replicated with r) ----
    half8 a0, a1;                           // A[m][k']: k' = 8hf+j (+16 for a1)
#pragma unroll
    for (int j = 0; j < 8; ++j) {
        a0[j] = (_Float16)__shfl(r, 8 * hf + j, 64);
        a1[j] = (_Float16)__shfl(r, 16 + 8 * hf + j, 64);
    }
    float ov[4];
#pragma unroll
    for (int t = 0; t < 4; ++t) {
        half8 b0, b1;                       // B[k'][n=l31] = fk[16kh+k'][32t+l31]
#pragma unroll
        for (int j = 0; j < 8; ++j) {
            b0[j] = fkRM[wave][8 * hf + j][32 * t + l31];
            b1[j] = fkRM[wave][16 + 8 * hf + j][32 * t + l31];
        }
        f32x16 oacc;
#pragma unroll
        for (int i = 0; i < 16; ++i) oacc[i] = 0.0f;
        oacc = __builtin_amdgcn_mfma_f32_32x32x16_f16(a0, b0, oacc, 0, 0, 0);
        oacc = __builtin_amdgcn_mfma_f32_32x32x16_f16(a1, b1, oacc, 0, 0, 0);
        ov[t] = oacc[0];                    // all C rows equal
    }
    // store 2 tiles per half-wave: hf=0 -> t=0,1 ; hf=1 -> t=2,3
#pragma unroll
    for (int u = 0; u < 2; ++u) {
        int t = 2 * hf + u;
        int d = 32 * t + l31;
        out[(size_t)node * DIM + d] = ov[t] + bias[d];
    }
}

extern "C" void kernel_launch(void* const* d_in, const int* in_sizes, int n_in,
                              void* d_out, int out_size, void* d_ws, size_t ws_size,
                              hipStream_t stream) {
    const float* feat = (const float*)d_in[0];
    const float* W    = (const float*)d_in[1];
    const float* bias = (const float*)d_in[2];
    const float* tkw  = (const float*)d_in[3];
    const int*   idx  = (const int*)d_in[4];
    float* out = (float*)d_out;

    const int n = in_sizes[0] / DIM;                       // 50000
    _Float16* hq = (_Float16*)d_ws;                        // n*128*2 = 12.8 MB
    _Float16* wt = hq + (size_t)n * DIM;                   // 32 KB

    prep<<<64, 256, 0, stream>>>(W, wt);
    gemm128<<<(n + 127) / 128, 256, 0, stream>>>(feat, wt, hq, n);
    softk<<<(n + 1) / 2, 128, 0, stream>>>(hq, bias, tkw, idx, out, n);
}